// Round 2
// baseline (426.132 us; speedup 1.0000x reference)
//
#include <hip/hip_runtime.h>
#include <math.h>
#include <stdint.h>

// Problem constants (fixed by the reference):
#define NQ 4096    // queries
#define MP 65536   // manifold points
#define DD 64      // dims
#define QT 64      // queries per block (2 nt tiles of 32)
#define STRIPES 8  // point stripes == XCDs; stripe s runs on XCD s (b&7 heuristic)
#define PPB (MP / STRIPES)      // 8192 points per stripe
#define GPS32 (PPB / 32)        // 256 groups (of 32 points) per stripe
#define PG32 (MP / 32)          // 2048 point groups
#define XG32 (NQ / 32)          // 128 query groups

typedef _Float16 f16;
typedef _Float16 f16x8 __attribute__((ext_vector_type(8)));
typedef float f32x4 __attribute__((ext_vector_type(4)));
typedef float f32x16 __attribute__((ext_vector_type(16)));

// 32x32x16 fragment layout (per 32-row group g):
//   FR[(((g*2 + sel)*4 + t)*512 + lane*8]  : 8 f16 = 16 B per lane
//   sel: 0=hi, 1=lo ; t: K-step (k = t*16 + (lane>>5)*8 + j) ; lane&31 = row.
//   Same per-lane octet rule as the R3-validated 16x16x32 layout, scaled to
//   32 rows x 2 k-octets. C/D: col=lane&31, row=(reg&3)+8*(reg>>2)+4*(lane>>5).

// One-shot pre-swizzle: fp32 rows -> hi/lo fp16 fragment order; also -0.5*|p|^2
// (negative, so it can seed the MFMA accumulator directly).
// Tasks 0..2047 = P groups, 2048..2175 = X groups. 4 groups per block (1/wave).
// X-task waves also initialize the 'best' keys (replaces the hipMemsetAsync).
__global__ __launch_bounds__(256) void prep_k(const float* __restrict__ P,
                                              const float* __restrict__ X,
                                              f16* __restrict__ PF,
                                              f16* __restrict__ XF,
                                              float* __restrict__ pnh,
                                              unsigned long long* __restrict__ best) {
    const int w = threadIdx.x >> 6, lane = threadIdx.x & 63;
    const int r32 = lane & 31, hi = lane >> 5;
    const int task = blockIdx.x * 4 + w;
    const float* src; f16* dst; int g; bool isP;
    if (task < PG32) { src = P; dst = PF; g = task; isP = true; }
    else             { src = X; dst = XF; g = task - PG32; isP = false; }

    const float* row = src + ((size_t)g * 32 + r32) * DD;
    float ss = 0.f;
    #pragma unroll
    for (int t = 0; t < 4; ++t) {
        float4 v0 = *reinterpret_cast<const float4*>(row + t * 16 + hi * 8);
        float4 v1 = *reinterpret_cast<const float4*>(row + t * 16 + hi * 8 + 4);
        float vv[8] = {v0.x, v0.y, v0.z, v0.w, v1.x, v1.y, v1.z, v1.w};
        f16x8 h, l;
        #pragma unroll
        for (int j = 0; j < 8; ++j) {
            f16 hh = (f16)vv[j];
            h[j] = hh;
            l[j] = (f16)(vv[j] - (float)hh);
            ss = fmaf(vv[j], vv[j], ss);
        }
        *reinterpret_cast<f16x8*>(dst + (((size_t)g * 2 + 0) * 4 + t) * 512 + lane * 8) = h;
        *reinterpret_cast<f16x8*>(dst + (((size_t)g * 2 + 1) * 4 + t) * 512 + lane * 8) = l;
    }
    if (isP) {
        ss += __shfl_xor(ss, 32);   // partner lane holds the other k-octets of this row
        if (hi == 0) pnh[g * 32 + r32] = -0.5f * ss;
    } else {
        int q = g * 64 + lane;      // 128 waves x 64 lanes = 8192 >= NQ
        if (q < NQ) best[q] = 0xFFFFFFFFFFFFFFFFULL;
    }
}

// Fused split-fp16 MFMA dot + argmax, zero LDS / zero barriers.
// score' = x.p - 0.5|p|^2 (maximize); x.p via ah*bh + ah*bl + al*bh;
// the -0.5|p|^2 bias rides in as the accumulator C-in (free add).
// Block 256 = 4 waves; each wave: 64 queries x (its quarter of the stripe).
// Grid 512 = 64 qtiles x 8 stripes; stripe = b&7 -> one stripe per XCD,
// PF stripe (2 MB) stays L2-resident for the whole kernel.
__global__ __launch_bounds__(256, 2) void argmin_k(const f16* __restrict__ PF,
                                                   const f16* __restrict__ XF,
                                                   const float* __restrict__ pnh,
                                                   unsigned long long* __restrict__ best) {
    const int t = threadIdx.x;
    const int lane = t & 63, w = t >> 6;
    const int col = lane & 31, hi = lane >> 5;
    const int b = blockIdx.x;
    const int stripe = b & 7;
    const int qBase = (b >> 3) * QT;

    // Query fragments, held in registers for the whole kernel. 2 tiles of 32.
    f16x8 QH[2][4], QL[2][4];
    {
        const int qg0 = qBase >> 5;
        #pragma unroll
        for (int nt = 0; nt < 2; ++nt)
            #pragma unroll
            for (int k = 0; k < 4; ++k) {
                const f16* o = XF + (size_t)(qg0 + nt) * 4096 + k * 512 + lane * 8;
                QH[nt][k] = *reinterpret_cast<const f16x8*>(o);
                QL[nt][k] = *reinterpret_cast<const f16x8*>(o + 2048);
            }
    }

    float rmax[2] = {-INFINITY, -INFINITY};
    int   ridx[2] = {0, 0};

    auto LOADG = [&](int gg, f16x8* PH, f16x8* PL, f32x4* B) {
        const f16* f0 = PF + (size_t)gg * 4096 + lane * 8;
        #pragma unroll
        for (int k = 0; k < 4; ++k) {
            PH[k] = *reinterpret_cast<const f16x8*>(f0 + k * 512);
            PL[k] = *reinterpret_cast<const f16x8*>(f0 + 2048 + k * 512);
        }
        // Bias fragment: rows for chunk rr are 8*rr + 4*hi + (0..3) -> plain
        // row-order pnh serves the C/D layout with 4 broadcast f32x4 loads.
        const float* pb = pnh + gg * 32 + hi * 4;
        #pragma unroll
        for (int rr = 0; rr < 4; ++rr)
            B[rr] = *reinterpret_cast<const f32x4*>(pb + rr * 8);
    };

    auto PROC = [&](int gg, f16x8* PH, f16x8* PL, f32x4* B) {
        #pragma unroll
        for (int nt = 0; nt < 2; ++nt) {
            f32x16 a;
            #pragma unroll
            for (int rr = 0; rr < 4; ++rr) {
                a[rr * 4 + 0] = B[rr][0]; a[rr * 4 + 1] = B[rr][1];
                a[rr * 4 + 2] = B[rr][2]; a[rr * 4 + 3] = B[rr][3];
            }
            __builtin_amdgcn_s_setprio(1);   // T5: barrier-free waves, MFMA cluster
            #pragma unroll
            for (int k = 0; k < 4; ++k) {
                a = __builtin_amdgcn_mfma_f32_32x32x16_f16(PH[k], QH[nt][k], a, 0, 0, 0);
                a = __builtin_amdgcn_mfma_f32_32x32x16_f16(PH[k], QL[nt][k], a, 0, 0, 0);
                a = __builtin_amdgcn_mfma_f32_32x32x16_f16(PL[k], QH[nt][k], a, 0, 0, 0);
            }
            __builtin_amdgcn_s_setprio(0);
            float m0 = fmaxf(fmaxf(a[0], a[1]),  fmaxf(a[2], a[3]));
            float m1 = fmaxf(fmaxf(a[4], a[5]),  fmaxf(a[6], a[7]));
            float m2 = fmaxf(fmaxf(a[8], a[9]),  fmaxf(a[10], a[11]));
            float m3 = fmaxf(fmaxf(a[12], a[13]), fmaxf(a[14], a[15]));
            float smax = fmaxf(fmaxf(m0, m1), fmaxf(m2, m3));
            // reg->row is monotone within a hi-half, so lowest reg == lowest row.
            int rsel = 15;
            #pragma unroll
            for (int r = 14; r >= 0; --r) rsel = (a[r] == smax) ? r : rsel;
            if (smax > rmax[nt]) {      // strict > keeps earliest (lowest) group
                rmax[nt] = smax;
                ridx[nt] = gg * 32 + (rsel & 3) + 8 * (rsel >> 2) + 4 * hi;
            }
        }
    };

    // Double-buffered group loop: wave w covers groups stripe*GPS32 + w + 4*j.
    int g = stripe * GPS32 + w;
    f16x8 PHa[4], PLa[4], PHb[4], PLb[4];
    f32x4 Ba[4], Bb[4];
    LOADG(g, PHa, PLa, Ba);
    #pragma unroll 1
    for (int i = 0; i < GPS32 / 4; i += 2) {
        LOADG(g + 4, PHb, PLb, Bb);          // prefetch group g+4
        PROC(g, PHa, PLa, Ba);
        {   // prefetch group g+8 (tail-guarded, re-reads g)
            int gp = (i + 2 < GPS32 / 4) ? g + 8 : g;
            LOADG(gp, PHa, PLa, Ba);
        }
        PROC(g + 4, PHb, PLb, Bb);
        g += 8;
    }

    // Reduce across the two hi-halves (lane bit 5): larger score', tie -> lower idx.
    #pragma unroll
    for (int nt = 0; nt < 2; ++nt) {
        float sv = rmax[nt]; int iv = ridx[nt];
        float so = __shfl_xor(sv, 32);
        int   io = __shfl_xor(iv, 32);
        if (so > sv || (so == sv && io < iv)) { sv = so; iv = io; }
        if (hi == 0) {
            float s = -2.f * sv;                       // back to d^2-|x|^2 scale
            unsigned u = __float_as_uint(s);
            u = (u & 0x80000000u) ? ~u : (u | 0x80000000u);
            unsigned long long key = ((unsigned long long)u << 32) | (unsigned)iv;
            atomicMin(&best[qBase + nt * 32 + col], key);
        }
    }
}

// Gather winning rows to out. 16 threads/query, coalesced float4 in/out.
__global__ __launch_bounds__(256) void gather_k(const unsigned long long* __restrict__ best,
                                                const float* __restrict__ P,
                                                float* __restrict__ out) {
    int g = blockIdx.x * 256 + threadIdx.x;  // NQ*16 threads
    int q = g >> 4, c = g & 15;
    unsigned idx = (unsigned)best[q];        // low 32 bits = index
    reinterpret_cast<float4*>(out)[g] =
        reinterpret_cast<const float4*>(P)[(size_t)idx * 16 + c];
}

extern "C" void kernel_launch(void* const* d_in, const int* in_sizes, int n_in,
                              void* d_out, int out_size, void* d_ws, size_t ws_size,
                              hipStream_t stream) {
    const float* X = (const float*)d_in[0];            // (4096, 64) f32
    const float* P = (const float*)d_in[1];            // (65536, 64) f32
    // d_in[2], d_in[3] unused by the reference output.
    float* out = (float*)d_out;                        // (4096, 64) f32

    // Workspace layout (all 16B-aligned):
    //   best @ 0           : NQ * 8 B        = 32 KB
    //   pnh  @ 32768       : MP * 4 B        = 256 KB   (-0.5*|p|^2)
    //   XF   @ 294912      : NQ*DD*2*2 B     = 1 MB     (query frags hi/lo)
    //   PF   @ 1343488     : MP*DD*2*2 B     = 16 MB    (point frags hi/lo)
    unsigned long long* best = (unsigned long long*)d_ws;
    float* pnh = (float*)((char*)d_ws + 32768);
    f16*   XF  = (f16*)((char*)d_ws + 294912);
    f16*   PF  = (f16*)((char*)d_ws + 1343488);

    prep_k<<<(PG32 + XG32) / 4, 256, 0, stream>>>(P, X, PF, XF, pnh, best);

    argmin_k<<<(NQ / QT) * STRIPES, 256, 0, stream>>>(PF, XF, pnh, best);

    gather_k<<<NQ * 16 / 256, 256, 0, stream>>>(best, P, out);
}